// Round 2
// baseline (6394.902 us; speedup 1.0000x reference)
//
#include <hip/hip_runtime.h>
#include <math.h>

namespace {

constexpr int kHid = 512;
constexpr int kRank = 4;
constexpr int kIn = 3;
constexpr int kOut = 3;
constexpr int kBatch = 128;
constexpr int kSeq = 1000;
constexpr float kNoiseStd = 0.05f;
constexpr float kTau = 0.2f;
constexpr int kBlock = 256;  // 4 waves, 2 h per thread
constexpr int kBHW = kBatch * kHid;

template <int CTRL>
__device__ __forceinline__ float dpp_add(float x) {
  int s = __builtin_amdgcn_update_dpp(0, __float_as_int(x), CTRL, 0xF, 0xF, true);
  return x + __int_as_float(s);
}

// All 4 lanes of each quad end with the quad sum.
__device__ __forceinline__ float quad_sum(float x) {
  x = dpp_add<0xB1>(x);  // quad_perm [1,0,3,2]  (xor 1)
  x = dpp_add<0x4E>(x);  // quad_perm [2,3,0,1]  (xor 2)
  return x;
}

__device__ __forceinline__ float tanh_fast(float x) {
  float e = __expf(2.0f * x);
  return fmaf(-2.0f, __builtin_amdgcn_rcpf(e + 1.0f), 1.0f);
}

__global__ __launch_bounds__(kBlock) void rnn_fused(
    const float* __restrict__ u, const float* __restrict__ x0,
    const float* __restrict__ noise, const float* __restrict__ Lw,
    const float* __restrict__ Mw, const float* __restrict__ Nw,
    const float* __restrict__ bias, const float* __restrict__ Win,
    const float* __restrict__ Wout, float* __restrict__ out,
    float* __restrict__ xfinal, float* __restrict__ traj) {
  const int b = blockIdx.x;
  const int tid = threadIdx.x;
  const int lane = tid & 63;
  const int h0 = tid * 2;

  __shared__ float uLds[kSeq * 4];              // u padded to stride 4 (16 KB)
  __shared__ __align__(16) float red[3][16];    // round-robin reduction buffers

  // Stage u for this batch into LDS (pad to stride 4 -> per-step b128 read).
  const float* ub = u + (size_t)b * kSeq * kIn;
  for (int i = tid; i < kSeq * kIn; i += kBlock) {
    int t = i / 3;
    uLds[t * 4 + (i - t * 3)] = ub[i];
  }
  if (tid < 12) ((float4*)red)[tid] = make_float4(0.f, 0.f, 0.f, 0.f);

  constexpr float inv_h2 = 1.0f / ((float)kHid * (float)kHid);

  float4 LA = *(const float4*)&Lw[(size_t)h0 * kRank];
  float4 LB = *(const float4*)&Lw[(size_t)(h0 + 1) * kRank];
  LA.x *= inv_h2; LA.y *= inv_h2; LA.z *= inv_h2; LA.w *= inv_h2;
  LB.x *= inv_h2; LB.y *= inv_h2; LB.z *= inv_h2; LB.w *= inv_h2;
  float4 MA = *(const float4*)&Mw[(size_t)h0 * kRank];
  float4 MB = *(const float4*)&Mw[(size_t)(h0 + 1) * kRank];
  float4 NA = *(const float4*)&Nw[(size_t)h0 * kRank];
  float4 NB = *(const float4*)&Nw[(size_t)(h0 + 1) * kRank];
  float WiA0 = Win[h0 * 3 + 0], WiA1 = Win[h0 * 3 + 1], WiA2 = Win[h0 * 3 + 2];
  float WiB0 = Win[(h0 + 1) * 3 + 0], WiB1 = Win[(h0 + 1) * 3 + 1],
        WiB2 = Win[(h0 + 1) * 3 + 2];
  float2 Wo0 = *(const float2*)&Wout[0 * kHid + h0];
  float2 Wo1 = *(const float2*)&Wout[1 * kHid + h0];
  float2 Wo2 = *(const float2*)&Wout[2 * kHid + h0];
  float2 bs = *(const float2*)&bias[h0];
  const bool bz = (bs.x == 0.f) && (bs.y == 0.f);

  float2 xv = *(const float2*)&x0[(size_t)b * kHid + h0];
  float xA = xv.x, xB = xv.y;

  float* trajB = traj + (size_t)b * (kSeq + 1) * kHid + h0;
  const size_t outBase = (size_t)b * kSeq * kOut;

  *(float2*)&trajB[0] = make_float2(xA, xB);  // trajectories[:,0,:] = x0

  // r0 = tanh(x0) WITHOUT bias (reference semantics)
  float rA = tanh_fast(xA), rB = tanh_fast(xB);
  float txA = 0.0f, txB = 0.0f;  // tanh(x_t) for out row; zero at t=0 (no row -1)

  const float* nsb = noise + (size_t)b * kHid + h0;
  float2 n0 = *(const float2*)&nsb[0];
  float2 n1 = *(const float2*)&nsb[(size_t)kBHW];
  float2 n2 = *(const float2*)&nsb[(size_t)2 * kBHW];

  __syncthreads();  // uLds + red zero ready

#define RNN_STEP(T, P, Z, NSLOT, PREFETCH)                                     \
  {                                                                            \
    const int t_ = (T);                                                        \
    float4 ut = *(const float4*)&uLds[t_ * 4];                                 \
    float2 nv = NSLOT;                                                         \
    if (PREFETCH) NSLOT = *(const float2*)&nsb[(size_t)(t_ + 3) * kBHW];       \
    float pm0 = fmaf(rB, MB.x, rA * MA.x);                                     \
    float pm1 = fmaf(rB, MB.y, rA * MA.y);                                     \
    float pm2 = fmaf(rB, MB.z, rA * MA.z);                                     \
    float pm3 = fmaf(rB, MB.w, rA * MA.w);                                     \
    float pn0 = fmaf(rB, NB.x, rA * NA.x);                                     \
    float pn1 = fmaf(rB, NB.y, rA * NA.y);                                     \
    float pn2 = fmaf(rB, NB.z, rA * NA.z);                                     \
    float pn3 = fmaf(rB, NB.w, rA * NA.w);                                     \
    float po0 = fmaf(txB, Wo0.y, txA * Wo0.x);                                 \
    float po1 = fmaf(txB, Wo1.y, txA * Wo1.x);                                 \
    float po2 = fmaf(txB, Wo2.y, txA * Wo2.x);                                 \
    pm0 = quad_sum(pm0); pm1 = quad_sum(pm1);                                  \
    pm2 = quad_sum(pm2); pm3 = quad_sum(pm3);                                  \
    pn0 = quad_sum(pn0); pn1 = quad_sum(pn1);                                  \
    pn2 = quad_sum(pn2); pn3 = quad_sum(pn3);                                  \
    po0 = quad_sum(po0); po1 = quad_sum(po1); po2 = quad_sum(po2);             \
    float inA = fmaf(ut.z, WiA2, fmaf(ut.y, WiA1, ut.x * WiA0));               \
    float inB = fmaf(ut.z, WiB2, fmaf(ut.y, WiB1, ut.x * WiB0));               \
    float xbA = fmaf(kTau, inA - xA, fmaf(kNoiseStd, nv.x, xA));               \
    float xbB = fmaf(kTau, inB - xB, fmaf(kNoiseStd, nv.y, xB));               \
    if ((lane & 3) == 0) {                                                     \
      float* rp = &red[(P)][0];                                                \
      atomicAdd(rp + 0, pm0); atomicAdd(rp + 1, pm1);                          \
      atomicAdd(rp + 2, pm2); atomicAdd(rp + 3, pm3);                          \
      atomicAdd(rp + 4, pn0); atomicAdd(rp + 5, pn1);                          \
      atomicAdd(rp + 6, pn2); atomicAdd(rp + 7, pn3);                          \
      atomicAdd(rp + 8, po0); atomicAdd(rp + 9, po1);                          \
      atomicAdd(rp + 10, po2);                                                 \
    }                                                                          \
    __syncthreads();                                                           \
    float4 rm = *(const float4*)&red[(P)][0];                                  \
    float4 rn = *(const float4*)&red[(P)][4];                                  \
    if (t_ > 0 && tid < 3)                                                     \
      out[outBase + (size_t)(t_ - 1) * kOut + tid] = red[(P)][8 + tid];        \
    if (tid < 4) *(float4*)&red[(Z)][tid * 4] = make_float4(0.f, 0.f, 0.f, 0.f); \
    float p0 = rm.x * rn.x, p1 = rm.y * rn.y;                                  \
    float p2 = rm.z * rn.z, p3 = rm.w * rn.w;                                  \
    float hidA = fmaf(p3, LA.w, fmaf(p2, LA.z, fmaf(p1, LA.y, p0 * LA.x)));    \
    float hidB = fmaf(p3, LB.w, fmaf(p2, LB.z, fmaf(p1, LB.y, p0 * LB.x)));    \
    xA = fmaf(kTau, hidA, xbA);                                                \
    xB = fmaf(kTau, hidB, xbB);                                                \
    *(float2*)&trajB[(size_t)(t_ + 1) * kHid] = make_float2(xA, xB);           \
    rA = tanh_fast(xA + bs.x);                                                 \
    rB = tanh_fast(xB + bs.y);                                                 \
    if (bz) { txA = rA; txB = rB; }                                            \
    else    { txA = tanh_fast(xA); txB = tanh_fast(xB); }                      \
  }

  int t = 0;
  for (int i = 0; i < 332; ++i) {  // t = 0 .. 995
    RNN_STEP(t, 0, 2, n0, true);
    RNN_STEP(t + 1, 1, 0, n1, true);
    RNN_STEP(t + 2, 2, 1, n2, true);
    t += 3;
  }
  // Tail: t = 996..999 (prefetch for 999 issued at 996; none after).
  RNN_STEP(996, 0, 2, n0, true);
  RNN_STEP(997, 1, 0, n1, false);
  RNN_STEP(998, 2, 1, n2, false);
  RNN_STEP(999, 0, 2, n0, false);
#undef RNN_STEP

  // Epilogue: out row SEQ-1 from tanh(x_SEQ). red[2] was zeroed at t=999;
  // extra barrier separates that zero from our adds.
  __syncthreads();
  {
    float po0 = fmaf(txB, Wo0.y, txA * Wo0.x);
    float po1 = fmaf(txB, Wo1.y, txA * Wo1.x);
    float po2 = fmaf(txB, Wo2.y, txA * Wo2.x);
    po0 = quad_sum(po0); po1 = quad_sum(po1); po2 = quad_sum(po2);
    if ((lane & 3) == 0) {
      atomicAdd(&red[2][8], po0);
      atomicAdd(&red[2][9], po1);
      atomicAdd(&red[2][10], po2);
    }
    __syncthreads();
    if (tid < 3)
      out[outBase + (size_t)(kSeq - 1) * kOut + tid] = red[2][8 + tid];
  }

  *(float2*)&xfinal[(size_t)b * kHid + h0] = make_float2(xA, xB);
}

}  // namespace

extern "C" void kernel_launch(void* const* d_in, const int* in_sizes, int n_in,
                              void* d_out, int out_size, void* d_ws,
                              size_t ws_size, hipStream_t stream) {
  const float* u = (const float*)d_in[0];      // (128, 1000, 3)
  const float* x0 = (const float*)d_in[1];     // (128, 512)
  const float* noise = (const float*)d_in[2];  // (1000, 128, 512)
  const float* Lw = (const float*)d_in[3];     // (512, 4)
  const float* Mw = (const float*)d_in[4];     // (512, 4)
  const float* Nw = (const float*)d_in[5];     // (512, 4)
  const float* bias = (const float*)d_in[6];   // (512,)
  const float* Win = (const float*)d_in[7];    // (512, 3)
  const float* Wout = (const float*)d_in[8];   // (3, 512)

  float* out = (float*)d_out;                           // (128, 1000, 3)
  float* xfinal = out + (size_t)kBatch * kSeq * kOut;   // (128, 512)
  float* traj = xfinal + (size_t)kBatch * kHid;         // (128, 1001, 512)

  rnn_fused<<<dim3(kBatch), dim3(kBlock), 0, stream>>>(
      u, x0, noise, Lw, Mw, Nw, bias, Win, Wout, out, xfinal, traj);
}

// Round 3
// 647.244 us; speedup vs baseline: 9.8802x; 9.8802x over previous
//
#include <hip/hip_runtime.h>
#include <math.h>

namespace {

constexpr int kHid = 512;
constexpr int kRank = 4;
constexpr int kIn = 3;
constexpr int kOut = 3;
constexpr int kBatch = 128;
constexpr int kSeq = 1000;
constexpr float kNoiseStd = 0.05f;
constexpr float kTau = 0.2f;
constexpr int kBlock = 256;  // 4 waves, 2 h per thread
constexpr int kBHW = kBatch * kHid;

template <int CTRL, int RMASK>
__device__ __forceinline__ float dpp_add(float x) {
  int s = __builtin_amdgcn_update_dpp(0, __float_as_int(x), CTRL, RMASK, 0xF, true);
  return x + __int_as_float(s);
}

// 6-stage wave sum; lane 63 (and lanes 48..63) hold the 64-lane total.
__device__ __forceinline__ float wave_sum63(float x) {
  x = dpp_add<0xB1, 0xF>(x);   // quad_perm xor1
  x = dpp_add<0x4E, 0xF>(x);   // quad_perm xor2
  x = dpp_add<0x141, 0xF>(x);  // row_half_mirror
  x = dpp_add<0x140, 0xF>(x);  // row_mirror
  x = dpp_add<0x142, 0xA>(x);  // row_bcast15 -> rows 1,3
  x = dpp_add<0x143, 0xC>(x);  // row_bcast31 -> rows 2,3
  return x;
}

__device__ __forceinline__ float tanh_fast(float x) {
  float e = __expf(2.0f * x);
  return fmaf(-2.0f, __builtin_amdgcn_rcpf(e + 1.0f), 1.0f);
}

__device__ __forceinline__ float4 add4(float4 a, float4 b) {
  return make_float4(a.x + b.x, a.y + b.y, a.z + b.z, a.w + b.w);
}

__global__ __launch_bounds__(kBlock) void rnn_fused(
    const float* __restrict__ u, const float* __restrict__ x0,
    const float* __restrict__ noise, const float* __restrict__ Lw,
    const float* __restrict__ Mw, const float* __restrict__ Nw,
    const float* __restrict__ bias, const float* __restrict__ Win,
    const float* __restrict__ Wout, float* __restrict__ out,
    float* __restrict__ xfinal, float* __restrict__ traj) {
  const int b = blockIdx.x;
  const int tid = threadIdx.x;
  const int lane = tid & 63;
  const int wid = tid >> 6;
  const int h0 = tid * 2;

  __shared__ float uLds[kSeq * 4];                      // u padded to stride 4
  __shared__ __align__(16) float wbuf[2][4][12];        // [parity][wave][value]

  // Stage u for this batch into LDS (pad to stride 4 -> per-step b128 read).
  const float* ub = u + (size_t)b * kSeq * kIn;
  for (int i = tid; i < kSeq * kIn; i += kBlock) {
    int t = i / 3;
    uLds[t * 4 + (i - t * 3)] = ub[i];
  }

  constexpr float inv_h2 = 1.0f / ((float)kHid * (float)kHid);

  float4 LA = *(const float4*)&Lw[(size_t)h0 * kRank];
  float4 LB = *(const float4*)&Lw[(size_t)(h0 + 1) * kRank];
  LA.x *= inv_h2; LA.y *= inv_h2; LA.z *= inv_h2; LA.w *= inv_h2;
  LB.x *= inv_h2; LB.y *= inv_h2; LB.z *= inv_h2; LB.w *= inv_h2;
  float4 MA = *(const float4*)&Mw[(size_t)h0 * kRank];
  float4 MB = *(const float4*)&Mw[(size_t)(h0 + 1) * kRank];
  float4 NA = *(const float4*)&Nw[(size_t)h0 * kRank];
  float4 NB = *(const float4*)&Nw[(size_t)(h0 + 1) * kRank];
  float WiA0 = Win[h0 * 3 + 0], WiA1 = Win[h0 * 3 + 1], WiA2 = Win[h0 * 3 + 2];
  float WiB0 = Win[(h0 + 1) * 3 + 0], WiB1 = Win[(h0 + 1) * 3 + 1],
        WiB2 = Win[(h0 + 1) * 3 + 2];
  float2 Wo0 = *(const float2*)&Wout[0 * kHid + h0];
  float2 Wo1 = *(const float2*)&Wout[1 * kHid + h0];
  float2 Wo2 = *(const float2*)&Wout[2 * kHid + h0];
  float2 bs = *(const float2*)&bias[h0];
  const bool bz = (bs.x == 0.f) && (bs.y == 0.f);

  float2 xv = *(const float2*)&x0[(size_t)b * kHid + h0];
  float xA = xv.x, xB = xv.y;

  float* trajB = traj + (size_t)b * (kSeq + 1) * kHid + h0;
  const size_t outBase = (size_t)b * kSeq * kOut;

  *(float2*)&trajB[0] = make_float2(xA, xB);  // trajectories[:,0,:] = x0

  // r0 = tanh(x0) WITHOUT bias (reference semantics)
  float rA = tanh_fast(xA), rB = tanh_fast(xB);
  float txA = 0.0f, txB = 0.0f;  // tanh(x_t); zero at t=0 (no out row -1)

  const float* nsb = noise + (size_t)b * kHid + h0;
  float2 n0 = *(const float2*)&nsb[0];
  float2 n1 = *(const float2*)&nsb[(size_t)kBHW];

  __syncthreads();  // uLds ready

  for (int t = 0; t < kSeq; ++t) {
    const int par = t & 1;

    float4 ut = *(const float4*)&uLds[t * 4];  // broadcast ds_read_b128
    float2 nv = n0;
    n0 = n1;
    int tp = (t + 2 < kSeq) ? t + 2 : kSeq - 1;
    n1 = *(const float2*)&nsb[(size_t)tp * kBHW];

    // Partials for 11 reductions.
    float pm0 = fmaf(rB, MB.x, rA * MA.x);
    float pm1 = fmaf(rB, MB.y, rA * MA.y);
    float pm2 = fmaf(rB, MB.z, rA * MA.z);
    float pm3 = fmaf(rB, MB.w, rA * MA.w);
    float pn0 = fmaf(rB, NB.x, rA * NA.x);
    float pn1 = fmaf(rB, NB.y, rA * NA.y);
    float pn2 = fmaf(rB, NB.z, rA * NA.z);
    float pn3 = fmaf(rB, NB.w, rA * NA.w);
    float po0 = fmaf(txB, Wo0.y, txA * Wo0.x);
    float po1 = fmaf(txB, Wo1.y, txA * Wo1.x);
    float po2 = fmaf(txB, Wo2.y, txA * Wo2.x);

    pm0 = wave_sum63(pm0); pm1 = wave_sum63(pm1);
    pm2 = wave_sum63(pm2); pm3 = wave_sum63(pm3);
    pn0 = wave_sum63(pn0); pn1 = wave_sum63(pn1);
    pn2 = wave_sum63(pn2); pn3 = wave_sum63(pn3);
    po0 = wave_sum63(po0); po1 = wave_sum63(po1); po2 = wave_sum63(po2);

    if (lane == 63) {
      float* wp = &wbuf[par][wid][0];
      wp[0] = pm0; wp[1] = pm1; wp[2] = pm2; wp[3] = pm3;
      wp[4] = pn0; wp[5] = pn1; wp[6] = pn2; wp[7] = pn3;
      wp[8] = po0; wp[9] = po1; wp[10] = po2;
    }

    // Hoisted state-independent part of the x update.
    float inA = fmaf(ut.z, WiA2, fmaf(ut.y, WiA1, ut.x * WiA0));
    float inB = fmaf(ut.z, WiB2, fmaf(ut.y, WiB1, ut.x * WiB0));
    float xbA = fmaf(kTau, inA - xA, fmaf(kNoiseStd, nv.x, xA));
    float xbB = fmaf(kTau, inB - xB, fmaf(kNoiseStd, nv.y, xB));

    __syncthreads();

    // Local combine of the 4 wave-partials (same-address broadcast reads).
    float4 a0 = *(const float4*)&wbuf[par][0][0];
    float4 a1 = *(const float4*)&wbuf[par][1][0];
    float4 a2 = *(const float4*)&wbuf[par][2][0];
    float4 a3 = *(const float4*)&wbuf[par][3][0];
    float4 b0 = *(const float4*)&wbuf[par][0][4];
    float4 b1 = *(const float4*)&wbuf[par][1][4];
    float4 b2 = *(const float4*)&wbuf[par][2][4];
    float4 b3 = *(const float4*)&wbuf[par][3][4];
    float4 rm = add4(add4(a0, a1), add4(a2, a3));
    float4 rn = add4(add4(b0, b1), add4(b2, b3));

    if (t > 0 && tid < 3) {
      out[outBase + (size_t)(t - 1) * kOut + tid] =
          ((wbuf[par][0][8 + tid] + wbuf[par][1][8 + tid]) +
           (wbuf[par][2][8 + tid] + wbuf[par][3][8 + tid]));
    }

    float p0 = rm.x * rn.x, p1 = rm.y * rn.y;
    float p2 = rm.z * rn.z, p3 = rm.w * rn.w;
    float hidA = fmaf(p3, LA.w, fmaf(p2, LA.z, fmaf(p1, LA.y, p0 * LA.x)));
    float hidB = fmaf(p3, LB.w, fmaf(p2, LB.z, fmaf(p1, LB.y, p0 * LB.x)));
    xA = fmaf(kTau, hidA, xbA);
    xB = fmaf(kTau, hidB, xbB);

    *(float2*)&trajB[(size_t)(t + 1) * kHid] = make_float2(xA, xB);

    rA = tanh_fast(xA + bs.x);
    rB = tanh_fast(xB + bs.y);
    if (bz) { txA = rA; txB = rB; }
    else    { txA = tanh_fast(xA); txB = tanh_fast(xB); }
  }

  // Epilogue: out row SEQ-1 from tanh(x_SEQ). Parity buffer (kSeq&1)=0 was
  // last read at t=999... use parity 0; a barrier separates prior reads.
  {
    float po0 = fmaf(txB, Wo0.y, txA * Wo0.x);
    float po1 = fmaf(txB, Wo1.y, txA * Wo1.x);
    float po2 = fmaf(txB, Wo2.y, txA * Wo2.x);
    po0 = wave_sum63(po0); po1 = wave_sum63(po1); po2 = wave_sum63(po2);
    __syncthreads();  // all prior reads of wbuf done
    if (lane == 63) {
      wbuf[0][wid][8] = po0; wbuf[0][wid][9] = po1; wbuf[0][wid][10] = po2;
    }
    __syncthreads();
    if (tid < 3) {
      out[outBase + (size_t)(kSeq - 1) * kOut + tid] =
          ((wbuf[0][0][8 + tid] + wbuf[0][1][8 + tid]) +
           (wbuf[0][2][8 + tid] + wbuf[0][3][8 + tid]));
    }
  }

  *(float2*)&xfinal[(size_t)b * kHid + h0] = make_float2(xA, xB);
}

}  // namespace

extern "C" void kernel_launch(void* const* d_in, const int* in_sizes, int n_in,
                              void* d_out, int out_size, void* d_ws,
                              size_t ws_size, hipStream_t stream) {
  const float* u = (const float*)d_in[0];      // (128, 1000, 3)
  const float* x0 = (const float*)d_in[1];     // (128, 512)
  const float* noise = (const float*)d_in[2];  // (1000, 128, 512)
  const float* Lw = (const float*)d_in[3];     // (512, 4)
  const float* Mw = (const float*)d_in[4];     // (512, 4)
  const float* Nw = (const float*)d_in[5];     // (512, 4)
  const float* bias = (const float*)d_in[6];   // (512,)
  const float* Win = (const float*)d_in[7];    // (512, 3)
  const float* Wout = (const float*)d_in[8];   // (3, 512)

  float* out = (float*)d_out;                           // (128, 1000, 3)
  float* xfinal = out + (size_t)kBatch * kSeq * kOut;   // (128, 512)
  float* traj = xfinal + (size_t)kBatch * kHid;         // (128, 1001, 512)

  rnn_fused<<<dim3(kBatch), dim3(kBlock), 0, stream>>>(
      u, x0, noise, Lw, Mw, Nw, bias, Win, Wout, out, xfinal, traj);
}